// Round 6
// baseline (231.714 us; speedup 1.0000x reference)
//
#include <hip/hip_runtime.h>

typedef _Float16 f16x8 __attribute__((ext_vector_type(8)));
typedef float f32x4 __attribute__((ext_vector_type(4)));
typedef float f32x16 __attribute__((ext_vector_type(16)));
typedef unsigned short u16;
typedef u16 u16x8 __attribute__((ext_vector_type(8)));
typedef u16 u16x4 __attribute__((ext_vector_type(4)));

// ---------- fp16 <-> fp32 helpers ----------
__device__ __forceinline__ u16 f2h_bits(float f) {
    _Float16 h = (_Float16)f;           // RNE
    return __builtin_bit_cast(u16, h);
}
__device__ __forceinline__ float h2f(u16 b) {
    return (float)__builtin_bit_cast(_Float16, b);
}

// async global->LDS, 16B per lane. LDS dest must be wave-uniform base +
// lane*16; per-thread t*16 satisfies that.
typedef __attribute__((address_space(1))) unsigned int gu32_as1;
typedef __attribute__((address_space(3))) unsigned int lu32_as3;
__device__ __forceinline__ void gload16(const u16* g, u16* l) {
    __builtin_amdgcn_global_load_lds((gu32_as1*)g, (lu32_as3*)l, 16, 0, 0);
}

// =====================================================================
// GEMM: C[M,N] = alpha * A[M,K] * Bt[N,K]^T  (fp16 bits, k-contiguous).
//
// ROUND-6: same structure as round 5 (256x256 tile, BK=32, 512 threads
// = 8 waves 2Mx4N, wave tile 128x64, 4-deep LDS rotation, counted
// vmcnt(8), raw barriers, no pinning) with ONE change: MFMA shape
// 16x16x32 -> 32x32x16. Rationale (rounds 0-5: five schedule variants
// all 52-66us, MfmaUtil 20-25% -> schedule-invariant): 32x32 ubench
// ceiling 2382 vs 2075 TF (+15%), HALF the MFMA instruction count at
// identical LDS read count/traffic, per-step MFMA pipe demand 1241 ->
// 1081 cyc.
//
// Wave tile 128x64 as 4x2 tiles of 32x32, acc[4][2] f32x16.
// Per wave per K-step: A 4 ti x 2 kk = 8 ds_read_b128, B 2x2 = 4,
// 16 x mfma_f32_32x32x16_f16.
//
// Fragment layouts (mirror of the verified 16x16 convention):
//   A: lane l holds A[m = l&31][k = (l>>5)*8 + j]   (8 contiguous k)
//   B: lane l holds Bt[n = l&31][k = (l>>5)*8 + j]
//   C/D (m74/m101): col = lane&31, row = (reg&3) + 8*(reg>>2) + 4*(lane>>5)
//
// LDS per matrix per buf: [row:256][slot:4][8] u16 (16 KB). Swizzle:
// slot s at row r holds global seg s^((r>>1)&3). Since frag rows are
// base + ti*32 + (lane&31) and 32 | ti*32, (row>>1)&3 = ((lane&31)>>1)&3.
// Frag seg for kk-half = kk*2 + (lane>>5); kk=1 pointer = kk=0 ^ 2.
// Bank check: 64 lanes x 4-bank spans cover 32 banks exactly 8x each
// (b128 minimum) -> conflict-free.
//
// Pipeline (unchanged from round 5): 4-deep rotation, stage tile k+3 at
// step k, s_waitcnt vmcnt(8) per step (tail: 4, 0), raw s_barrier.
//
// MODE: 0 plain store; 1 exp(alpha*s)+rowsum atomics; 2 QKV (bn<8 -> QK
// ldc=2048; bn>=8 -> V transposed into vt[1024][4096]).
// Requires Ksplit % 32 == 0, Ksplit/32 >= 3. gridDim.z = split-K.
// =====================================================================
template <int MODE>
__global__ __launch_bounds__(512, 2) void gemm_bt(
    const u16* __restrict__ A, int lda,
    const u16* __restrict__ B, int ldb,
    u16* __restrict__ C, int ldc,
    int Ksplit, float alpha, size_t c_z_stride,
    int bnW, int bmW, int numPanelX,
    float* __restrict__ rowsum, u16* __restrict__ vt)
{
    __shared__ __attribute__((aligned(16))) u16 As[32768];  // 4 x 16 KB
    __shared__ __attribute__((aligned(16))) u16 Bs[32768];  // 4 x 16 KB

    const int t    = threadIdx.x;        // 0..511
    const int lane = t & 63;
    const int wave = t >> 6;             // 0..7
    const int wm   = wave >> 2;          // 0..1  (128-row half)
    const int wn   = wave & 3;           // 0..3  (64-col quarter)
    const int l31  = lane & 31;
    const int kh   = lane >> 5;          // k-half selector in frags

    // 2D-panel XCD mapping (grid x*y divisible by 8)
    const int lin = blockIdx.y * gridDim.x + blockIdx.x;
    const int xcd = lin & 7;
    const int idx = lin >> 3;
    const int px  = xcd % numPanelX;
    const int py  = xcd / numPanelX;
    const int bn  = px * bnW + idx % bnW;
    const int bm  = py * bmW + idx / bnW;

    const int kz = blockIdx.z;
    A += (size_t)kz * Ksplit;
    B += (size_t)kz * Ksplit;
    C += (size_t)kz * c_z_stride;

    // staging: thread t -> row t>>2 (and +128), slot t&3; global seg
    // pre-swizzled so the linear LDS write lands swizzled. [0 conflicts]
    const int srow = t >> 2;
    const int sseg = ((t & 3) ^ ((t >> 3) & 3)) * 8;

    const u16* Ag = A + (size_t)(bm * 256 + srow) * lda + sseg;
    const u16* Bg = B + (size_t)(bn * 256 + srow) * ldb + sseg;
    const size_t a128 = (size_t)128 * lda;   // row+128: same swizzle term
    const size_t b128 = (size_t)128 * ldb;

    u16* AsD = &As[t * 8];
    u16* BsD = &Bs[t * 8];

    // tile kt (k-range [kt*32, kt*32+32)) -> buf bufv. 4 loads/thread.
#define STAGE(bufv, kt) do {                                       \
        const u16* _ga = Ag + (size_t)(kt) * 32;                   \
        const u16* _gb = Bg + (size_t)(kt) * 32;                   \
        u16* _la = AsD + (bufv) * 8192;                            \
        u16* _lb = BsD + (bufv) * 8192;                            \
        gload16(_ga,        _la);            /* A rows 0-127   */  \
        gload16(_ga + a128, _la + 4096);     /* A rows 128-255 */  \
        gload16(_gb,        _lb);            /* B rows 0-127   */  \
        gload16(_gb + b128, _lb + 4096);     /* B rows 128-255 */  \
    } while (0)

    // fragment base pointers. row = base + ti*32 + l31; slot for kk-half:
    // (kk*2 + kh) ^ ((l31>>1)&3); kk=1 slot = kk=0 slot ^ 2.
    const int swz = (l31 >> 1) & 3;
    const int sA0 = kh ^ swz;            // kk = 0
    const int sA1 = sA0 ^ 2;             // kk = 1
    const u16* AfrK0 = &As[(wm * 128 + l31) * 32 + sA0 * 8];
    const u16* AfrK1 = &As[(wm * 128 + l31) * 32 + sA1 * 8];
    const u16* BfrK0 = &Bs[(wn * 64 + l31) * 32 + sA0 * 8];
    const u16* BfrK1 = &Bs[(wn * 64 + l31) * 32 + sA1 * 8];

    f32x16 acc[4][2] = {};

    const int NT = Ksplit >> 5;

    // prologue: stage tiles 0,1,2; wait tile 0 only
    STAGE(0, 0);
    STAGE(1, 1);
    STAGE(2, 2);
    asm volatile("s_waitcnt vmcnt(8)" ::: "memory");
    __builtin_amdgcn_s_barrier();
    asm volatile("" ::: "memory");

    for (int k = 0; k < NT; ++k) {
        const int buf = k & 3;

        // ---- 12 fragment reads from buf ----
        f16x8 af[4][2], bf[2][2];
#pragma unroll
        for (int ti = 0; ti < 4; ti++) {
            af[ti][0] = *(const f16x8*)(AfrK0 + buf * 8192 + ti * 1024);
            af[ti][1] = *(const f16x8*)(AfrK1 + buf * 8192 + ti * 1024);
        }
#pragma unroll
        for (int tj = 0; tj < 2; tj++) {
            bf[tj][0] = *(const f16x8*)(BfrK0 + buf * 8192 + tj * 1024);
            bf[tj][1] = *(const f16x8*)(BfrK1 + buf * 8192 + tj * 1024);
        }

        // ---- stage tile k+3 into buf[(k+3)&3] (not read until k+3) ----
        if (k + 3 < NT) STAGE((k + 3) & 3, k + 3);

        // ---- 16 MFMA (32x32x16); compiler inserts counted lgkmcnt ----
#pragma unroll
        for (int ti = 0; ti < 4; ti++)
#pragma unroll
            for (int tj = 0; tj < 2; tj++)
#pragma unroll
                for (int kk = 0; kk < 2; kk++)
                    acc[ti][tj] = __builtin_amdgcn_mfma_f32_32x32x16_f16(
                        af[ti][kk], bf[tj][kk], acc[ti][tj], 0, 0, 0);

        // ---- counted wait: tile k+1 landed; k+2,k+3 stay in flight ----
        if (k < NT - 3)       asm volatile("s_waitcnt vmcnt(8)" ::: "memory");
        else if (k == NT - 3) asm volatile("s_waitcnt vmcnt(4)" ::: "memory");
        else if (k == NT - 2) asm volatile("s_waitcnt vmcnt(0)" ::: "memory");
        __builtin_amdgcn_s_barrier();
        asm volatile("" ::: "memory");   // compiler fence: reads stay below
    }
#undef STAGE

    // epilogue. C/D: col = l31 (+tj*32), row = crow0 + ti*32 + (r&3)+8*(r>>2)
    const int crow0 = bm * 256 + wm * 128 + kh * 4;
    const int ccol0 = bn * 256 + wn * 64 + l31;

    if (MODE == 1) {
#pragma unroll
        for (int ti = 0; ti < 4; ti++) {
#pragma unroll
            for (int r = 0; r < 16; r++) {
                const int row = crow0 + ti * 32 + (r & 3) + 8 * (r >> 2);
                float e0 = __expf(acc[ti][0][r] * alpha);
                float e1 = __expf(acc[ti][1][r] * alpha);
                C[(size_t)row * ldc + ccol0]      = f2h_bits(e0);
                C[(size_t)row * ldc + ccol0 + 32] = f2h_bits(e1);
                float s = e0 + e1;
#pragma unroll
                for (int o = 1; o < 32; o <<= 1) s += __shfl_xor(s, o);
                if (l31 == 0)
                    atomicAdd(&rowsum[row], s);
            }
        }
    } else if (MODE == 2 && bn >= 8) {
        // V tile -> write transposed into vt[1024][4096]
#pragma unroll
        for (int tj = 0; tj < 2; tj++) {
            const int cV = (bn - 8) * 256 + wn * 64 + tj * 32 + l31;
#pragma unroll
            for (int ti = 0; ti < 4; ti++) {
#pragma unroll
                for (int rg = 0; rg < 4; rg++) {
                    u16x4 o;
#pragma unroll
                    for (int rr = 0; rr < 4; rr++)
                        o[rr] = f2h_bits(acc[ti][tj][rg * 4 + rr]);
                    *(u16x4*)(vt + (size_t)cV * 4096 +
                              (crow0 + ti * 32 + 8 * rg)) = o;
                }
            }
        }
    } else {
#pragma unroll
        for (int ti = 0; ti < 4; ti++)
#pragma unroll
            for (int tj = 0; tj < 2; tj++)
#pragma unroll
                for (int r = 0; r < 16; r++) {
                    const int row = crow0 + ti * 32 + (r & 3) + 8 * (r >> 2);
                    C[(size_t)row * ldc + ccol0 + tj * 32] =
                        f2h_bits(acc[ti][tj][r] * alpha);
                }
    }
}

// =====================================================================
// cast fp32 -> fp16 bits, 4 elems/thread
// =====================================================================
__global__ __launch_bounds__(256) void cast_to_f16(
    const float* __restrict__ in, u16* __restrict__ out, int n)
{
    int i = (blockIdx.x * 256 + threadIdx.x) * 4;
    if (i + 3 < n) {
        float4 v = *(const float4*)(in + i);
        ushort4 o;
        o.x = f2h_bits(v.x);
        o.y = f2h_bits(v.y);
        o.z = f2h_bits(v.z);
        o.w = f2h_bits(v.w);
        *(ushort4*)(out + i) = o;
    }
}

// =====================================================================
// transpose the 3 weight matrices [1024][1024] fp32 -> packed fp16
// Wt[3072][1024]; z selects the matrix. 32x32 LDS tile, block (32,8).
// =====================================================================
__global__ __launch_bounds__(256) void transpose_w3(
    const float* __restrict__ W0, const float* __restrict__ W1,
    const float* __restrict__ W2, u16* __restrict__ out)
{
    const float* in = (blockIdx.z == 0) ? W0 : (blockIdx.z == 1) ? W1 : W2;
    u16* o = out + (size_t)blockIdx.z * 1024 * 1024;
    __shared__ float tile[32][33];
    const int bx = blockIdx.x * 32;
    const int by = blockIdx.y * 32;
    const int tx = threadIdx.x, ty = threadIdx.y;
#pragma unroll
    for (int j = 0; j < 4; j++)
        tile[ty + j * 8][tx] = in[(size_t)(by + ty + j * 8) * 1024 + bx + tx];
    __syncthreads();
#pragma unroll
    for (int j = 0; j < 4; j++)
        o[(size_t)(bx + ty + j * 8) * 1024 + by + tx] = f2h_bits(tile[tx][ty + j * 8]);
}

// =====================================================================
// zero a float array (n multiple of 1024)
// =====================================================================
__global__ __launch_bounds__(256) void zero_f32(float* __restrict__ p, int n)
{
    int i = (blockIdx.x * 256 + threadIdx.x) * 4;
    if (i + 3 < n) *(float4*)(p + i) = float4{0.f, 0.f, 0.f, 0.f};
}

// =====================================================================
// out = (P0+P1+P2+P3)/l[row]; partials fp16, 8 elems/thread
// =====================================================================
__global__ __launch_bounds__(256) void add_div4(
    const u16* __restrict__ P, const float* __restrict__ l,
    float* __restrict__ o)
{
    const size_t zs = (size_t)4096 * 1024;
    int i = (blockIdx.x * 256 + threadIdx.x) * 8;
    float inv = 1.0f / l[i >> 10];
    float s[8] = {};
#pragma unroll
    for (int z = 0; z < 4; z++) {
        u16x8 h = *(const u16x8*)(P + z * zs + i);
#pragma unroll
        for (int j = 0; j < 8; j++) s[j] += h2f(h[j]);
    }
    float4 lo{s[0] * inv, s[1] * inv, s[2] * inv, s[3] * inv};
    float4 hi{s[4] * inv, s[5] * inv, s[6] * inv, s[7] * inv};
    *(float4*)(o + i) = lo;
    *(float4*)(o + i + 4) = hi;
}

// =====================================================================
// launch
//
// Workspace liveness (MiB):
//   xb [0,8)    live 1-3          Wt [8,14)  live 2-3
//   QK [14,30)  live 3-5          Vt [64,72) live 3-6
//   Sb [32,64)  live 5-6          lr [72,+16K) zero 4, atomics 5, read 7
//   P  [0,32)   written 6 (xb/Wt/QK dead), read 7
// =====================================================================
extern "C" void kernel_launch(void* const* d_in, const int* in_sizes, int n_in,
                              void* d_out, int out_size, void* d_ws, size_t ws_size,
                              hipStream_t stream)
{
    (void)in_sizes; (void)n_in; (void)out_size; (void)ws_size;
    const float* x  = (const float*)d_in[0];
    const float* Wq = (const float*)d_in[1];
    const float* Wk = (const float*)d_in[2];
    const float* Wv = (const float*)d_in[3];
    float* out = (float*)d_out;
    char* ws = (char*)d_ws;

    u16* xb  = (u16*)(ws);                              //  8 MiB
    u16* Wt  = (u16*)(ws + ((size_t)8  << 20));         //  6 MiB
    u16* QK  = (u16*)(ws + ((size_t)14 << 20));         // 16 MiB [4096][2048]
    u16* Sb  = (u16*)(ws + ((size_t)32 << 20));         // 32 MiB [4096][4096]
    u16* Vt  = (u16*)(ws + ((size_t)64 << 20));         //  8 MiB [1024][4096]
    float* lr = (float*)(ws + ((size_t)72 << 20));      // 16 KiB row sums
    u16* P   = (u16*)(ws);                              // 32 MiB: 4 x [4096][1024]

    const int S = 4096, D = 1024;
    dim3 tb(32, 8);

    // 1) cast x to fp16
    cast_to_f16<<<(S * D) / (4 * 256), 256, 0, stream>>>(x, xb, S * D);

    // 2) transpose-cast all three W's into packed Wt[3072][1024]
    transpose_w3<<<dim3(32, 32, 3), tb, 0, stream>>>(Wq, Wk, Wv, Wt);

    // 3) [Q|K] = x @ [Wq|Wk], V^T written directly (M=4096, N=3072, K=1024)
    //    grid 12x16=192 blocks; panels: bnW=3, bmW=8, numPanelX=4
    gemm_bt<2><<<dim3(12, 16, 1), 512, 0, stream>>>(
        xb, D, Wt, D, QK, 2048, D, 1.0f, 0, 3, 8, 4, nullptr, Vt);

    // 4) zero row-sum accumulator
    zero_f32<<<S / (4 * 256), 256, 0, stream>>>(lr, S);

    // 5) Sb = exp((Q @ K^T)/32) + rowsum atomics  (M=N=4096, K=1024)
    //    grid 16x16=256 blocks; panels: bnW=4, bmW=8, numPanelX=4
    gemm_bt<1><<<dim3(16, 16, 1), 512, 0, stream>>>(
        QK, 2048, QK + 1024, 2048, Sb, S, D, 0.03125f, 0, 4, 8, 4, lr, nullptr);

    // 6) P[z] = expS @ V, split-K=4 (M=4096, N=1024, Ksplit=1024 of K=4096)
    //    grid 4x16x4; panels per z: bnW=1, bmW=8, numPanelX=4
    gemm_bt<0><<<dim3(4, 16, 4), 512, 0, stream>>>(
        Sb, S, Vt, S, P, D, 1024, 1.0f, (size_t)S * D, 1, 8, 4, nullptr, nullptr);

    // 7) out = (P0+P1+P2+P3) / l[row]
    add_div4<<<(S * D) / (8 * 256), 256, 0, stream>>>(P, lr, out);
}

// Round 8
// 216.357 us; speedup vs baseline: 1.0710x; 1.0710x over previous
//
#include <hip/hip_runtime.h>

typedef _Float16 f16x8 __attribute__((ext_vector_type(8)));
typedef float f32x4 __attribute__((ext_vector_type(4)));
typedef unsigned short u16;
typedef u16 u16x8 __attribute__((ext_vector_type(8)));
typedef u16 u16x4 __attribute__((ext_vector_type(4)));

// ---------- fp16 <-> fp32 helpers ----------
__device__ __forceinline__ u16 f2h_bits(float f) {
    _Float16 h = (_Float16)f;           // RNE
    return __builtin_bit_cast(u16, h);
}
__device__ __forceinline__ float h2f(u16 b) {
    return (float)__builtin_bit_cast(_Float16, b);
}

// async global->LDS, 16B per lane (dest = wave-uniform base + lane*16).
typedef __attribute__((address_space(1))) unsigned int gu32_as1;
typedef __attribute__((address_space(3))) unsigned int lu32_as3;
__device__ __forceinline__ void gload16(const u16* g, u16* l) {
    __builtin_amdgcn_global_load_lds((gu32_as1*)g, (lu32_as3*)l, 16, 0, 0);
}

// =====================================================================
// GEMM: C[M,N] = alpha * A[M,K] * Bt[N,K]^T  (fp16 bits, k-contiguous).
//
// ROUND-8 (= round-7 resubmitted; GPU acquisition timed out, kernel
// never ran): faithful port of the verified 256^2 8-phase template
// (m201; m248: at K=1024 this structure = 848 TF vs 2-phase 655 — all
// seven of our prior variants measured exactly 2-phase-class). Deltas
// vs our failed round-1 approximation: NO sched_barrier(0) (m141:
// -42%), lgkmcnt(0) AFTER the phase barrier (not before), 1 half-tile
// staged per phase (2 gloads, fine interleave), vmcnt(4) only at P4/P8.
//
// Geometry: 256x256 tile, BK=64, 512 threads = 8 waves (2M x 4N), wave
// tile 128x64 = acc[8][4] f32x4 via mfma_f32_16x16x32_f16. Iteration =
// 2 K-tiles (t0=2it even -> LDS buf0, t1 odd -> buf1), 8 phases; phase
// = one C-quadrant (mh,nh) x K=64 = 16 MFMA.
//   P1: rd A(mh0)+B(nh0) buf0 | stage Ah0-buf1[t1]   | MFMA Q(0,0)
//   P2: rd B(nh1) buf0        | stage Ah1-buf1[t1]   | Q(0,1)
//   P3: rd A(mh1) buf0        | stage Bh0-buf0[t0+2] | Q(1,0)
//   P4: -                     | stage Bh1-buf0[t0+2] | Q(1,1) vmcnt(4)
//   P5-P8: same on buf1/t1; stages: Ah0,Ah1-buf0[t0+2], Bh0,Bh1-buf1[t1+2];
//          vmcnt(4) at P8.
// Phase sync: {reads; stage} BARRIER lgkmcnt(0) setprio(1) MFMA
// setprio(0) [vmcnt] BARRIER.   NO sched_barrier anywhere.
//
// Ledger (slot death -> stage; stage -> landing -> first read):
//   deaths: B-buf0 after P2, A-buf0 after P3, B-buf1 after P6, A-buf1
//   after P7 (lgkmcnt(0) before MFMA + phase-end barrier publish).
//   landings: vmcnt(4) leaves exactly the last 2 stages in flight, so
//   at P4: P7,P8(it-1),P1,P2(it) landed -> covers P5-P7 reads + next-P1;
//   at P8: P3..P6(it) landed -> covers P1-P3(it+1). Last iter: P3-P8
//   stages skipped, vmcnt(0) at P4 (P1,P2 must land for P5) and P8.
// Prologue: stage buf0[t0] x4 + Bh0,Bh1-buf1[t1]; vmcnt(4); barrier.
//
// LDS (128 KiB): per matrix [buf:2][half:2][row:128][seg:8][8] u16
// (half-tile = 16 KB; strides u16: buf 16384, half 8192, row 64, seg 8).
// Swizzle: LDS seg s at row r holds global seg s^(r&7). Staged linearly
// (thread t -> positions t, t+512; global seg pre-swizzled
// (t&7)^((t>>3)&7)); read at seg (kk*4+quad)^(l16&7). Bank check: 64
// lanes x 4 banks = 256 touches, uniform 8 per bank -> conflict-free.
// Global staging: 8 lanes/row cover a permuted contiguous 128B -> fully
// coalesced.
//
// MODE: 0 plain store; 1 exp(alpha*s)+rowsum atomics; 2 QKV (bn<8 -> QK
// ldc=2048; bn>=8 -> V transposed into vt[1024][4096]).
// Requires Ksplit % 128 == 0, Ksplit/128 >= 2. gridDim.z = split-K.
// =====================================================================
#define BAR   __builtin_amdgcn_s_barrier()
#define LGK0  asm volatile("s_waitcnt lgkmcnt(0)" ::: "memory")
#define VM4   asm volatile("s_waitcnt vmcnt(4)" ::: "memory")
#define VM0   asm volatile("s_waitcnt vmcnt(0)" ::: "memory")
#define PRIO1 __builtin_amdgcn_s_setprio(1)
#define PRIO0 __builtin_amdgcn_s_setprio(0)

template <int MODE>
__global__ __launch_bounds__(512, 2) void gemm_bt(
    const u16* __restrict__ A, int lda,
    const u16* __restrict__ B, int ldb,
    u16* __restrict__ C, int ldc,
    int Ksplit, float alpha, size_t c_z_stride,
    int bnW, int bmW, int numPanelX,
    float* __restrict__ rowsum, u16* __restrict__ vt)
{
    __shared__ __attribute__((aligned(16))) u16 As[32768];  // 64 KB
    __shared__ __attribute__((aligned(16))) u16 Bs[32768];  // 64 KB

    const int t    = threadIdx.x;        // 0..511
    const int lane = t & 63;
    const int wave = t >> 6;             // 0..7
    const int wm   = wave >> 2;          // 0..1  (128-row half)
    const int wn   = wave & 3;           // 0..3  (64-col quarter)
    const int l16  = lane & 15;
    const int quad = lane >> 4;

    // 2D-panel XCD mapping (grid x*y divisible by 8)
    const int lin = blockIdx.y * gridDim.x + blockIdx.x;
    const int xcd = lin & 7;
    const int idx = lin >> 3;
    const int px  = xcd % numPanelX;
    const int py  = xcd / numPanelX;
    const int bn  = px * bnW + idx % bnW;
    const int bm  = py * bmW + idx / bnW;

    const int kz = blockIdx.z;
    A += (size_t)kz * Ksplit;
    B += (size_t)kz * Ksplit;
    C += (size_t)kz * c_z_stride;

    // staging addressing: thread t -> rows t>>3 and (t>>3)+64 of a half,
    // 16B seg (t&7); global seg pre-swizzled: (t&7)^((t>>3)&7).
    const int srow = t >> 3;
    const int sseg = ((t & 7) ^ ((t >> 3) & 7)) * 8;
    const u16* Ag = A + (size_t)(bm * 256 + srow) * lda + sseg;
    const u16* Bg = B + (size_t)(bn * 256 + srow) * ldb + sseg;
    u16* AsD = &As[t * 8];
    u16* BsD = &Bs[t * 8];

#define STG_A(h, bufv, kt) do {                                         \
        const u16* _s = Ag + (size_t)(h) * 128 * lda + (size_t)(kt) * 64; \
        u16* _d = AsD + (bufv) * 16384 + (h) * 8192;                    \
        gload16(_s, _d);                                                \
        gload16(_s + (size_t)64 * lda, _d + 4096);                      \
    } while (0)
#define STG_B(h, bufv, kt) do {                                         \
        const u16* _s = Bg + (size_t)(h) * 128 * ldb + (size_t)(kt) * 64; \
        u16* _d = BsD + (bufv) * 16384 + (h) * 8192;                    \
        gload16(_s, _d);                                                \
        gload16(_s + (size_t)64 * ldb, _d + 4096);                      \
    } while (0)

    // fragment read addressing: row' (in half) = sub*16 + l16 (+mh*64),
    // u16 off = row'*64 + ((kk*4+quad)^(l16&7))*8
    const int skz = l16 & 7;
    const int sk0 = (quad ^ skz) * 8;
    const int sk1 = ((4 + quad) ^ skz) * 8;
    const u16* Ab = As + wm * 8192 + l16 * 64;
    const u16* Bb = Bs + (wn >> 1) * 8192 + (wn & 1) * 4096 + l16 * 64;

#define RD_A(dst, mh, bufv) do {                                        \
        _Pragma("unroll") for (int mi = 0; mi < 4; mi++) {              \
            dst[mi][0] = *(const f16x8*)(Ab + (bufv) * 16384 +          \
                                         (mh) * 4096 + mi * 1024 + sk0);\
            dst[mi][1] = *(const f16x8*)(Ab + (bufv) * 16384 +          \
                                         (mh) * 4096 + mi * 1024 + sk1);\
        } } while (0)
#define RD_B(dst, nh, bufv) do {                                        \
        _Pragma("unroll") for (int nj = 0; nj < 2; nj++) {              \
            dst[nj][0] = *(const f16x8*)(Bb + (bufv) * 16384 +          \
                                         (nh) * 2048 + nj * 1024 + sk0);\
            dst[nj][1] = *(const f16x8*)(Bb + (bufv) * 16384 +          \
                                         (nh) * 2048 + nj * 1024 + sk1);\
        } } while (0)
#define MFQ(mh, nh, Af, Bf) do {                                        \
        _Pragma("unroll") for (int mi = 0; mi < 4; mi++)                \
        _Pragma("unroll") for (int nj = 0; nj < 2; nj++)                \
        _Pragma("unroll") for (int kk = 0; kk < 2; kk++)                \
            acc[(mh)*4+mi][(nh)*2+nj] =                                 \
                __builtin_amdgcn_mfma_f32_16x16x32_f16(                 \
                    Af[mi][kk], Bf[nj][kk], acc[(mh)*4+mi][(nh)*2+nj],  \
                    0, 0, 0);                                           \
    } while (0)

    f32x4 acc[8][4] = {};
    const int NI = Ksplit >> 7;   // 2 K-tiles (BK=64) per iteration

    // prologue: buf0 <- tile 0 (all 4 halves); buf1 <- tile 1 B-halves
    STG_A(0, 0, 0); STG_A(1, 0, 0); STG_B(0, 0, 0); STG_B(1, 0, 0);
    STG_B(0, 1, 1); STG_B(1, 1, 1);
    VM4;            // buf0 complete; B-buf1 (2 stages) in flight
    BAR;

    for (int it = 0; it < NI; ++it) {
        const int t0 = it * 2, t1 = it * 2 + 1;
        const bool nl = (it + 1 < NI);
        f16x8 a0[4][2], a1[4][2], b0[2][2], b1[2][2];

        // ---- P1 ----
        RD_A(a0, 0, 0); RD_B(b0, 0, 0);
        STG_A(0, 1, t1);
        BAR; LGK0; PRIO1; MFQ(0, 0, a0, b0); PRIO0; BAR;
        // ---- P2 ----
        RD_B(b1, 1, 0);
        STG_A(1, 1, t1);
        BAR; LGK0; PRIO1; MFQ(0, 1, a0, b1); PRIO0; BAR;
        // ---- P3 ----
        RD_A(a1, 1, 0);
        if (nl) STG_B(0, 0, t0 + 2);
        BAR; LGK0; PRIO1; MFQ(1, 0, a1, b0); PRIO0; BAR;
        // ---- P4 ----
        if (nl) STG_B(1, 0, t0 + 2);
        BAR; LGK0; PRIO1; MFQ(1, 1, a1, b1); PRIO0;
        if (nl) VM4; else VM0;
        BAR;
        // ---- P5 ----
        RD_A(a0, 0, 1); RD_B(b0, 0, 1);
        if (nl) STG_A(0, 0, t0 + 2);
        BAR; LGK0; PRIO1; MFQ(0, 0, a0, b0); PRIO0; BAR;
        // ---- P6 ----
        RD_B(b1, 1, 1);
        if (nl) STG_A(1, 0, t0 + 2);
        BAR; LGK0; PRIO1; MFQ(0, 1, a0, b1); PRIO0; BAR;
        // ---- P7 ----
        RD_A(a1, 1, 1);
        if (nl) STG_B(0, 1, t1 + 2);
        BAR; LGK0; PRIO1; MFQ(1, 0, a1, b0); PRIO0; BAR;
        // ---- P8 ----
        if (nl) STG_B(1, 1, t1 + 2);
        BAR; LGK0; PRIO1; MFQ(1, 1, a1, b1); PRIO0;
        if (nl) VM4; else VM0;
        BAR;
    }
#undef STG_A
#undef STG_B
#undef RD_A
#undef RD_B
#undef MFQ

    // epilogue: C/D layout col = lane&15, row = quad*4 + reg
    const int crow = bm * 256 + wm * 128 + quad * 4;
    const int ccol = bn * 256 + wn * 64 + l16;

    if (MODE == 1) {
        float rs[8][4];
#pragma unroll
        for (int mi = 0; mi < 8; mi++)
#pragma unroll
            for (int r = 0; r < 4; r++) rs[mi][r] = 0.f;
#pragma unroll
        for (int mi = 0; mi < 8; mi++) {
#pragma unroll
            for (int ni = 0; ni < 4; ni++) {
#pragma unroll
                for (int r = 0; r < 4; r++) {
                    float e = __expf(acc[mi][ni][r] * alpha);
                    rs[mi][r] += e;
                    C[(size_t)(crow + mi * 16 + r) * ldc + (ccol + ni * 16)] = f2h_bits(e);
                }
            }
        }
#pragma unroll
        for (int mi = 0; mi < 8; mi++) {
#pragma unroll
            for (int r = 0; r < 4; r++) {
                float s = rs[mi][r];
#pragma unroll
                for (int o = 1; o < 16; o <<= 1) s += __shfl_xor(s, o);
                if (l16 == 0)
                    atomicAdd(&rowsum[crow + mi * 16 + r], s);
            }
        }
    } else if (MODE == 2 && bn >= 8) {
        // V tile -> write transposed into vt[1024][4096]
#pragma unroll
        for (int ni = 0; ni < 4; ni++) {
            const int cV = (bn - 8) * 256 + wn * 64 + ni * 16 + l16;
#pragma unroll
            for (int mi = 0; mi < 8; mi++) {
                u16x4 o;
#pragma unroll
                for (int r = 0; r < 4; r++) o[r] = f2h_bits(acc[mi][ni][r]);
                *(u16x4*)(vt + (size_t)cV * 4096 + crow + mi * 16) = o;
            }
        }
    } else {
#pragma unroll
        for (int mi = 0; mi < 8; mi++)
#pragma unroll
            for (int ni = 0; ni < 4; ni++)
#pragma unroll
                for (int r = 0; r < 4; r++)
                    C[(size_t)(crow + mi * 16 + r) * ldc + (ccol + ni * 16)] =
                        f2h_bits(acc[mi][ni][r] * alpha);
    }
}

// =====================================================================
// cast fp32 -> fp16 bits, 4 elems/thread
// =====================================================================
__global__ __launch_bounds__(256) void cast_to_f16(
    const float* __restrict__ in, u16* __restrict__ out, int n)
{
    int i = (blockIdx.x * 256 + threadIdx.x) * 4;
    if (i + 3 < n) {
        float4 v = *(const float4*)(in + i);
        ushort4 o;
        o.x = f2h_bits(v.x);
        o.y = f2h_bits(v.y);
        o.z = f2h_bits(v.z);
        o.w = f2h_bits(v.w);
        *(ushort4*)(out + i) = o;
    }
}

// =====================================================================
// transpose the 3 weight matrices [1024][1024] fp32 -> packed fp16
// Wt[3072][1024]; z selects the matrix. 32x32 LDS tile, block (32,8).
// =====================================================================
__global__ __launch_bounds__(256) void transpose_w3(
    const float* __restrict__ W0, const float* __restrict__ W1,
    const float* __restrict__ W2, u16* __restrict__ out)
{
    const float* in = (blockIdx.z == 0) ? W0 : (blockIdx.z == 1) ? W1 : W2;
    u16* o = out + (size_t)blockIdx.z * 1024 * 1024;
    __shared__ float tile[32][33];
    const int bx = blockIdx.x * 32;
    const int by = blockIdx.y * 32;
    const int tx = threadIdx.x, ty = threadIdx.y;
#pragma unroll
    for (int j = 0; j < 4; j++)
        tile[ty + j * 8][tx] = in[(size_t)(by + ty + j * 8) * 1024 + bx + tx];
    __syncthreads();
#pragma unroll
    for (int j = 0; j < 4; j++)
        o[(size_t)(bx + ty + j * 8) * 1024 + by + tx] = f2h_bits(tile[tx][ty + j * 8]);
}

// =====================================================================
// zero a float array (n multiple of 1024)
// =====================================================================
__global__ __launch_bounds__(256) void zero_f32(float* __restrict__ p, int n)
{
    int i = (blockIdx.x * 256 + threadIdx.x) * 4;
    if (i + 3 < n) *(float4*)(p + i) = float4{0.f, 0.f, 0.f, 0.f};
}

// =====================================================================
// out = (P0+P1+P2+P3)/l[row]; partials fp16, 8 elems/thread
// =====================================================================
__global__ __launch_bounds__(256) void add_div4(
    const u16* __restrict__ P, const float* __restrict__ l,
    float* __restrict__ o)
{
    const size_t zs = (size_t)4096 * 1024;
    int i = (blockIdx.x * 256 + threadIdx.x) * 8;
    float inv = 1.0f / l[i >> 10];
    float s[8] = {};
#pragma unroll
    for (int z = 0; z < 4; z++) {
        u16x8 h = *(const u16x8*)(P + z * zs + i);
#pragma unroll
        for (int j = 0; j < 8; j++) s[j] += h2f(h[j]);
    }
    float4 lo{s[0] * inv, s[1] * inv, s[2] * inv, s[3] * inv};
    float4 hi{s[4] * inv, s[5] * inv, s[6] * inv, s[7] * inv};
    *(float4*)(o + i) = lo;
    *(float4*)(o + i + 4) = hi;
}

// =====================================================================
// launch
//
// Workspace liveness (MiB):
//   xb [0,8)    live 1-3          Wt [8,14)  live 2-3
//   QK [14,30)  live 3-5          Vt [64,72) live 3-6
//   Sb [32,64)  live 5-6          lr [72,+16K) zero 4, atomics 5, read 7
//   P  [0,32)   written 6 (xb/Wt/QK dead), read 7
// =====================================================================
extern "C" void kernel_launch(void* const* d_in, const int* in_sizes, int n_in,
                              void* d_out, int out_size, void* d_ws, size_t ws_size,
                              hipStream_t stream)
{
    (void)in_sizes; (void)n_in; (void)out_size; (void)ws_size;
    const float* x  = (const float*)d_in[0];
    const float* Wq = (const float*)d_in[1];
    const float* Wk = (const float*)d_in[2];
    const float* Wv = (const float*)d_in[3];
    float* out = (float*)d_out;
    char* ws = (char*)d_ws;

    u16* xb  = (u16*)(ws);                              //  8 MiB
    u16* Wt  = (u16*)(ws + ((size_t)8  << 20));         //  6 MiB
    u16* QK  = (u16*)(ws + ((size_t)14 << 20));         // 16 MiB [4096][2048]
    u16* Sb  = (u16*)(ws + ((size_t)32 << 20));         // 32 MiB [4096][4096]
    u16* Vt  = (u16*)(ws + ((size_t)64 << 20));         //  8 MiB [1024][4096]
    float* lr = (float*)(ws + ((size_t)72 << 20));      // 16 KiB row sums
    u16* P   = (u16*)(ws);                              // 32 MiB: 4 x [4096][1024]

    const int S = 4096, D = 1024;
    dim3 tb(32, 8);

    // 1) cast x to fp16
    cast_to_f16<<<(S * D) / (4 * 256), 256, 0, stream>>>(x, xb, S * D);

    // 2) transpose-cast all three W's into packed Wt[3072][1024]
    transpose_w3<<<dim3(32, 32, 3), tb, 0, stream>>>(Wq, Wk, Wv, Wt);

    // 3) [Q|K] = x @ [Wq|Wk], V^T written directly (M=4096, N=3072, K=1024)
    //    grid 12x16=192 blocks; panels: bnW=3, bmW=8, numPanelX=4
    gemm_bt<2><<<dim3(12, 16, 1), 512, 0, stream>>>(
        xb, D, Wt, D, QK, 2048, D, 1.0f, 0, 3, 8, 4, nullptr, Vt);

    // 4) zero row-sum accumulator
    zero_f32<<<S / (4 * 256), 256, 0, stream>>>(lr, S);

    // 5) Sb = exp((Q @ K^T)/32) + rowsum atomics  (M=N=4096, K=1024)
    //    grid 16x16=256 blocks; panels: bnW=4, bmW=8, numPanelX=4
    gemm_bt<1><<<dim3(16, 16, 1), 512, 0, stream>>>(
        QK, 2048, QK + 1024, 2048, Sb, S, D, 0.03125f, 0, 4, 8, 4, lr, nullptr);

    // 6) P[z] = expS @ V, split-K=4 (M=4096, N=1024, Ksplit=1024 of K=4096)
    //    grid 4x16x4; panels per z: bnW=1, bmW=8, numPanelX=4
    gemm_bt<0><<<dim3(4, 16, 4), 512, 0, stream>>>(
        Sb, S, Vt, S, P, D, 1024, 1.0f, (size_t)S * D, 1, 8, 4, nullptr, nullptr);

    // 7) out = (P0+P1+P2+P3) / l[row]
    add_div4<<<(S * D) / (8 * 256), 256, 0, stream>>>(P, lr, out);
}

// Round 9
// 210.962 us; speedup vs baseline: 1.0984x; 1.0256x over previous
//
#include <hip/hip_runtime.h>

typedef _Float16 f16x8 __attribute__((ext_vector_type(8)));
typedef float f32x4 __attribute__((ext_vector_type(4)));
typedef unsigned short u16;
typedef u16 u16x8 __attribute__((ext_vector_type(8)));
typedef u16 u16x4 __attribute__((ext_vector_type(4)));

// ---------- fp16 <-> fp32 helpers ----------
__device__ __forceinline__ u16 f2h_bits(float f) {
    _Float16 h = (_Float16)f;           // RNE
    return __builtin_bit_cast(u16, h);
}
__device__ __forceinline__ float h2f(u16 b) {
    return (float)__builtin_bit_cast(_Float16, b);
}

// async global->LDS, 16B per lane (dest = wave-uniform base + lane*16).
typedef __attribute__((address_space(1))) unsigned int gu32_as1;
typedef __attribute__((address_space(3))) unsigned int lu32_as3;
__device__ __forceinline__ void gload16(const u16* g, u16* l) {
    __builtin_amdgcn_global_load_lds((gu32_as1*)g, (lu32_as3*)l, 16, 0, 0);
}

// =====================================================================
// GEMM: C[M,N] = alpha * A[M,K] * Bt[N,K]^T  (fp16 bits, k-contiguous).
//
// ROUND-9: round-8's 8-phase template + the ONE remaining delta vs the
// verified m201 template: PREFETCH DEPTH. Template holds 3 half-tiles
// in flight (vmcnt(6) at P4/P8); round-8 held 2 (vmcnt(4)) with 3-5
// phase stage->use gaps. Re-derived stage schedule with HALF-granular
// death tracking (each half-tile is dead after its last-reader phase's
// end barrier, one phase earlier than coarse tracking):
//   P1: stage Ah1-buf1[t1]      (Ah1-buf1 dead after P7 of it-1)
//   P2: stage Bh0-buf0[t0+2]    (Bh0-buf0 last read P1)
//   P3: stage Ah0-buf0[t0+2]    (Ah0-buf0 last read P1)
//   P4: stage Bh1-buf0[t0+2]    (Bh1-buf0 last read P2)   vmcnt(6)
//   P5: stage Ah1-buf0[t0+2]    (Ah1-buf0 last read P3)
//   P6: stage Bh0-buf1[t1+2]    (Bh0-buf1 last read P5)
//   P7: stage Ah0-buf1[t1+2]    (Ah0-buf1 last read P5)
//   P8: stage Bh1-buf1[t1+2]    (Bh1-buf1 last read P6)   vmcnt(6)
// Landing proof: stage->read pairs P1->P7, P2->P1', P3->P1', P4->P2',
// P5->P3', P6->P5', P7->P5', P8->P6'. vmcnt(6) at P4 leaves exactly
// {P2,P3,P4} outstanding -> P1 landed (covers P7) and all older (P5-P7
// reads). vmcnt(6) at P8 leaves {P6,P7,P8} -> P5 landed (covers P3'),
// P4 (P2'), P2,P3 (P1'). Uniform 6-load steady state = template's
// "N = 2 loads x 3 half-tiles in flight".
// Tail: last iter stages only P1 (needed for its own P7); vmcnt(0) at
// P4/P8. Second-to-last normal; its stages are guarded by last-iter
// vmcnt(0)@P4 and prior vmcnt(6)s (checked per pair above).
// Prologue: buf0[0] all 4 halves + buf1[1] Bh0,Ah0,Bh1 (7 stages);
// vmcnt(6) leaves buf1's 3 -> buf0 landed; BAR.
//
// Phase sync: {reads; stage} BARRIER lgkmcnt(0) setprio(1) 16xMFMA
// setprio(0) [vmcnt] BARRIER.  No sched_barrier anywhere (m141).
//
// Geometry: 256x256 tile, BK=64, 512 threads = 8 waves (2M x 4N), wave
// tile 128x64 = acc[8][4] f32x4 via mfma_f32_16x16x32_f16. Iteration =
// 2 K-tiles (t0 -> buf0, t1 -> buf1); phase = one C-quadrant x K=64.
//
// LDS (128 KiB): per matrix [buf:2][half:2][row:128][seg:8][8] u16
// (strides u16: buf 16384, half 8192, row 64, seg 8). Swizzle: LDS seg
// s at row r holds global seg s^(r&7); staged linearly (global seg
// pre-swizzled (t&7)^((t>>3)&7)); read at seg (kk*4+quad)^(l16&7).
// Bank-uniform (8 touches/bank) -> conflict-free (measured 0).
//
// MODE: 0 plain store; 1 exp(alpha*s)+rowsum atomics; 2 QKV (bn<8 -> QK
// ldc=2048; bn>=8 -> V transposed into vt[1024][4096]).
// Requires Ksplit % 128 == 0, Ksplit/128 >= 2. gridDim.z = split-K.
// =====================================================================
#define BAR   __builtin_amdgcn_s_barrier()
#define LGK0  asm volatile("s_waitcnt lgkmcnt(0)" ::: "memory")
#define VM6   asm volatile("s_waitcnt vmcnt(6)" ::: "memory")
#define VM0   asm volatile("s_waitcnt vmcnt(0)" ::: "memory")
#define PRIO1 __builtin_amdgcn_s_setprio(1)
#define PRIO0 __builtin_amdgcn_s_setprio(0)

template <int MODE>
__global__ __launch_bounds__(512, 2) void gemm_bt(
    const u16* __restrict__ A, int lda,
    const u16* __restrict__ B, int ldb,
    u16* __restrict__ C, int ldc,
    int Ksplit, float alpha, size_t c_z_stride,
    int bnW, int bmW, int numPanelX,
    float* __restrict__ rowsum, u16* __restrict__ vt)
{
    __shared__ __attribute__((aligned(16))) u16 As[32768];  // 64 KB
    __shared__ __attribute__((aligned(16))) u16 Bs[32768];  // 64 KB

    const int t    = threadIdx.x;        // 0..511
    const int lane = t & 63;
    const int wave = t >> 6;             // 0..7
    const int wm   = wave >> 2;          // 0..1  (128-row half)
    const int wn   = wave & 3;           // 0..3  (64-col quarter)
    const int l16  = lane & 15;
    const int quad = lane >> 4;

    // 2D-panel XCD mapping (grid x*y divisible by 8)
    const int lin = blockIdx.y * gridDim.x + blockIdx.x;
    const int xcd = lin & 7;
    const int idx = lin >> 3;
    const int px  = xcd % numPanelX;
    const int py  = xcd / numPanelX;
    const int bn  = px * bnW + idx % bnW;
    const int bm  = py * bmW + idx / bnW;

    const int kz = blockIdx.z;
    A += (size_t)kz * Ksplit;
    B += (size_t)kz * Ksplit;
    C += (size_t)kz * c_z_stride;

    // staging addressing: thread t -> rows t>>3 and (t>>3)+64 of a half,
    // 16B seg (t&7); global seg pre-swizzled: (t&7)^((t>>3)&7).
    const int srow = t >> 3;
    const int sseg = ((t & 7) ^ ((t >> 3) & 7)) * 8;
    const u16* Ag = A + (size_t)(bm * 256 + srow) * lda + sseg;
    const u16* Bg = B + (size_t)(bn * 256 + srow) * ldb + sseg;
    u16* AsD = &As[t * 8];
    u16* BsD = &Bs[t * 8];

#define STG_A(h, bufv, kt) do {                                         \
        const u16* _s = Ag + (size_t)(h) * 128 * lda + (size_t)(kt) * 64; \
        u16* _d = AsD + (bufv) * 16384 + (h) * 8192;                    \
        gload16(_s, _d);                                                \
        gload16(_s + (size_t)64 * lda, _d + 4096);                      \
    } while (0)
#define STG_B(h, bufv, kt) do {                                         \
        const u16* _s = Bg + (size_t)(h) * 128 * ldb + (size_t)(kt) * 64; \
        u16* _d = BsD + (bufv) * 16384 + (h) * 8192;                    \
        gload16(_s, _d);                                                \
        gload16(_s + (size_t)64 * ldb, _d + 4096);                      \
    } while (0)

    // fragment read addressing: row' (in half) = sub*16 + l16 (+mh*64),
    // u16 off = row'*64 + ((kk*4+quad)^(l16&7))*8
    const int skz = l16 & 7;
    const int sk0 = (quad ^ skz) * 8;
    const int sk1 = ((4 + quad) ^ skz) * 8;
    const u16* Ab = As + wm * 8192 + l16 * 64;
    const u16* Bb = Bs + (wn >> 1) * 8192 + (wn & 1) * 4096 + l16 * 64;

#define RD_A(dst, mh, bufv) do {                                        \
        _Pragma("unroll") for (int mi = 0; mi < 4; mi++) {              \
            dst[mi][0] = *(const f16x8*)(Ab + (bufv) * 16384 +          \
                                         (mh) * 4096 + mi * 1024 + sk0);\
            dst[mi][1] = *(const f16x8*)(Ab + (bufv) * 16384 +          \
                                         (mh) * 4096 + mi * 1024 + sk1);\
        } } while (0)
#define RD_B(dst, nh, bufv) do {                                        \
        _Pragma("unroll") for (int nj = 0; nj < 2; nj++) {              \
            dst[nj][0] = *(const f16x8*)(Bb + (bufv) * 16384 +          \
                                         (nh) * 2048 + nj * 1024 + sk0);\
            dst[nj][1] = *(const f16x8*)(Bb + (bufv) * 16384 +          \
                                         (nh) * 2048 + nj * 1024 + sk1);\
        } } while (0)
#define MFQ(mh, nh, Af, Bf) do {                                        \
        _Pragma("unroll") for (int mi = 0; mi < 4; mi++)                \
        _Pragma("unroll") for (int nj = 0; nj < 2; nj++)                \
        _Pragma("unroll") for (int kk = 0; kk < 2; kk++)                \
            acc[(mh)*4+mi][(nh)*2+nj] =                                 \
                __builtin_amdgcn_mfma_f32_16x16x32_f16(                 \
                    Af[mi][kk], Bf[nj][kk], acc[(mh)*4+mi][(nh)*2+nj],  \
                    0, 0, 0);                                           \
    } while (0)

    f32x4 acc[8][4] = {};
    const int NI = Ksplit >> 7;   // 2 K-tiles (BK=64) per iteration

    // prologue: buf0[0] all halves; buf1[1] Bh0, Ah0, Bh1 (Ah1 at P1)
    STG_A(0, 0, 0); STG_A(1, 0, 0); STG_B(0, 0, 0); STG_B(1, 0, 0);
    STG_B(0, 1, 1); STG_A(0, 1, 1); STG_B(1, 1, 1);
    VM6;            // buf0 complete; buf1's 3 stages in flight
    BAR;

    for (int it = 0; it < NI; ++it) {
        const int t0 = it * 2, t1 = it * 2 + 1;
        const bool nl = (it + 1 < NI);
        f16x8 a0[4][2], a1[4][2], b0[2][2], b1[2][2];

        // ---- P1 ----
        RD_A(a0, 0, 0); RD_B(b0, 0, 0);
        STG_A(1, 1, t1);                       // always: used at P7
        BAR; LGK0; PRIO1; MFQ(0, 0, a0, b0); PRIO0; BAR;
        // ---- P2 ----
        RD_B(b1, 1, 0);
        if (nl) STG_B(0, 0, t0 + 2);
        BAR; LGK0; PRIO1; MFQ(0, 1, a0, b1); PRIO0; BAR;
        // ---- P3 ----
        RD_A(a1, 1, 0);
        if (nl) STG_A(0, 0, t0 + 2);
        BAR; LGK0; PRIO1; MFQ(1, 0, a1, b0); PRIO0; BAR;
        // ---- P4 ----
        if (nl) STG_B(1, 0, t0 + 2);
        BAR; LGK0; PRIO1; MFQ(1, 1, a1, b1); PRIO0;
        if (nl) VM6; else VM0;
        BAR;
        // ---- P5 ----
        RD_A(a0, 0, 1); RD_B(b0, 0, 1);
        if (nl) STG_A(1, 0, t0 + 2);
        BAR; LGK0; PRIO1; MFQ(0, 0, a0, b0); PRIO0; BAR;
        // ---- P6 ----
        RD_B(b1, 1, 1);
        if (nl) STG_B(0, 1, t1 + 2);
        BAR; LGK0; PRIO1; MFQ(0, 1, a0, b1); PRIO0; BAR;
        // ---- P7 ----
        RD_A(a1, 1, 1);
        if (nl) STG_A(0, 1, t1 + 2);
        BAR; LGK0; PRIO1; MFQ(1, 0, a1, b0); PRIO0; BAR;
        // ---- P8 ----
        if (nl) STG_B(1, 1, t1 + 2);
        BAR; LGK0; PRIO1; MFQ(1, 1, a1, b1); PRIO0;
        if (nl) VM6; else VM0;
        BAR;
    }
#undef STG_A
#undef STG_B
#undef RD_A
#undef RD_B
#undef MFQ

    // epilogue: C/D layout col = lane&15, row = quad*4 + reg
    const int crow = bm * 256 + wm * 128 + quad * 4;
    const int ccol = bn * 256 + wn * 64 + l16;

    if (MODE == 1) {
        float rs[8][4];
#pragma unroll
        for (int mi = 0; mi < 8; mi++)
#pragma unroll
            for (int r = 0; r < 4; r++) rs[mi][r] = 0.f;
#pragma unroll
        for (int mi = 0; mi < 8; mi++) {
#pragma unroll
            for (int ni = 0; ni < 4; ni++) {
#pragma unroll
                for (int r = 0; r < 4; r++) {
                    float e = __expf(acc[mi][ni][r] * alpha);
                    rs[mi][r] += e;
                    C[(size_t)(crow + mi * 16 + r) * ldc + (ccol + ni * 16)] = f2h_bits(e);
                }
            }
        }
#pragma unroll
        for (int mi = 0; mi < 8; mi++) {
#pragma unroll
            for (int r = 0; r < 4; r++) {
                float s = rs[mi][r];
#pragma unroll
                for (int o = 1; o < 16; o <<= 1) s += __shfl_xor(s, o);
                if (l16 == 0)
                    atomicAdd(&rowsum[crow + mi * 16 + r], s);
            }
        }
    } else if (MODE == 2 && bn >= 8) {
        // V tile -> write transposed into vt[1024][4096]
#pragma unroll
        for (int ni = 0; ni < 4; ni++) {
            const int cV = (bn - 8) * 256 + wn * 64 + ni * 16 + l16;
#pragma unroll
            for (int mi = 0; mi < 8; mi++) {
                u16x4 o;
#pragma unroll
                for (int r = 0; r < 4; r++) o[r] = f2h_bits(acc[mi][ni][r]);
                *(u16x4*)(vt + (size_t)cV * 4096 + crow + mi * 16) = o;
            }
        }
    } else {
#pragma unroll
        for (int mi = 0; mi < 8; mi++)
#pragma unroll
            for (int ni = 0; ni < 4; ni++)
#pragma unroll
                for (int r = 0; r < 4; r++)
                    C[(size_t)(crow + mi * 16 + r) * ldc + (ccol + ni * 16)] =
                        f2h_bits(acc[mi][ni][r] * alpha);
    }
}

// =====================================================================
// prep: fused cast_to_f16 + transpose_w3 + zero(lr) in ONE launch.
// grid.x = 4096 (cast) + 3072 (transpose, 3 z x 1024 tiles) + 4 (zero).
// 256 threads. Each block takes exactly one branch (uniform per block).
// =====================================================================
__global__ __launch_bounds__(256) void prep(
    const float* __restrict__ x, u16* __restrict__ xb,
    const float* __restrict__ W0, const float* __restrict__ W1,
    const float* __restrict__ W2, u16* __restrict__ Wt,
    float* __restrict__ lr)
{
    __shared__ float tile[32][33];
    const int bid = blockIdx.x;
    const int t   = threadIdx.x;

    if (bid < 4096) {
        // cast x fp32 -> fp16 bits, 4 elems/thread (4096*1024 total)
        int i = (bid * 256 + t) * 4;
        float4 v = *(const float4*)(x + i);
        ushort4 o;
        o.x = f2h_bits(v.x);
        o.y = f2h_bits(v.y);
        o.z = f2h_bits(v.z);
        o.w = f2h_bits(v.w);
        *(ushort4*)(xb + i) = o;
    } else if (bid < 4096 + 3072) {
        // transpose-cast W[z] 32x32 tile
        const int b   = bid - 4096;
        const int z   = b >> 10;
        const int rem = b & 1023;
        const float* in = (z == 0) ? W0 : (z == 1) ? W1 : W2;
        u16* o = Wt + (size_t)z * 1024 * 1024;
        const int bx = (rem & 31) * 32;
        const int by = (rem >> 5) * 32;
        const int tx = t & 31, ty = t >> 5;   // 32 x 8
#pragma unroll
        for (int j = 0; j < 4; j++)
            tile[ty + j * 8][tx] = in[(size_t)(by + ty + j * 8) * 1024 + bx + tx];
        __syncthreads();
#pragma unroll
        for (int j = 0; j < 4; j++)
            o[(size_t)(bx + ty + j * 8) * 1024 + by + tx] = f2h_bits(tile[tx][ty + j * 8]);
    } else {
        // zero lr (4096 floats)
        int i = ((bid - 4096 - 3072) * 256 + t) * 4;
        *(float4*)(lr + i) = float4{0.f, 0.f, 0.f, 0.f};
    }
}

// =====================================================================
// out = (P0+P1+P2+P3)/l[row]; partials fp16, 8 elems/thread
// =====================================================================
__global__ __launch_bounds__(256) void add_div4(
    const u16* __restrict__ P, const float* __restrict__ l,
    float* __restrict__ o)
{
    const size_t zs = (size_t)4096 * 1024;
    int i = (blockIdx.x * 256 + threadIdx.x) * 8;
    float inv = 1.0f / l[i >> 10];
    float s[8] = {};
#pragma unroll
    for (int z = 0; z < 4; z++) {
        u16x8 h = *(const u16x8*)(P + z * zs + i);
#pragma unroll
        for (int j = 0; j < 8; j++) s[j] += h2f(h[j]);
    }
    float4 lo{s[0] * inv, s[1] * inv, s[2] * inv, s[3] * inv};
    float4 hi{s[4] * inv, s[5] * inv, s[6] * inv, s[7] * inv};
    *(float4*)(o + i) = lo;
    *(float4*)(o + i + 4) = hi;
}

// =====================================================================
// launch
//
// Workspace liveness (MiB):
//   xb [0,8)    live 1-2          Wt [8,14)  live 1-2
//   QK [14,30)  live 2-4          Vt [64,72) live 2-5
//   Sb [32,64)  live 4-5          lr [72,+16K) zero 1, atomics 4, read 6
//   P  [0,32)   written 5 (xb/Wt/QK dead), read 6
// =====================================================================
extern "C" void kernel_launch(void* const* d_in, const int* in_sizes, int n_in,
                              void* d_out, int out_size, void* d_ws, size_t ws_size,
                              hipStream_t stream)
{
    (void)in_sizes; (void)n_in; (void)out_size; (void)ws_size;
    const float* x  = (const float*)d_in[0];
    const float* Wq = (const float*)d_in[1];
    const float* Wk = (const float*)d_in[2];
    const float* Wv = (const float*)d_in[3];
    float* out = (float*)d_out;
    char* ws = (char*)d_ws;

    u16* xb  = (u16*)(ws);                              //  8 MiB
    u16* Wt  = (u16*)(ws + ((size_t)8  << 20));         //  6 MiB
    u16* QK  = (u16*)(ws + ((size_t)14 << 20));         // 16 MiB [4096][2048]
    u16* Sb  = (u16*)(ws + ((size_t)32 << 20));         // 32 MiB [4096][4096]
    u16* Vt  = (u16*)(ws + ((size_t)64 << 20));         //  8 MiB [1024][4096]
    float* lr = (float*)(ws + ((size_t)72 << 20));      // 16 KiB row sums
    u16* P   = (u16*)(ws);                              // 32 MiB: 4 x [4096][1024]

    const int S = 4096, D = 1024;

    // 1) fused prep: cast x, transpose-cast W's, zero lr (one launch)
    prep<<<4096 + 3072 + 4, 256, 0, stream>>>(x, xb, Wq, Wk, Wv, Wt, lr);

    // 2) [Q|K] = x @ [Wq|Wk], V^T written directly (M=4096, N=3072, K=1024)
    //    grid 12x16=192 blocks; panels: bnW=3, bmW=8, numPanelX=4
    gemm_bt<2><<<dim3(12, 16, 1), 512, 0, stream>>>(
        xb, D, Wt, D, QK, 2048, D, 1.0f, 0, 3, 8, 4, nullptr, Vt);

    // 3) Sb = exp((Q @ K^T)/32) + rowsum atomics  (M=N=4096, K=1024)
    //    grid 16x16=256 blocks; panels: bnW=4, bmW=8, numPanelX=4
    gemm_bt<1><<<dim3(16, 16, 1), 512, 0, stream>>>(
        QK, 2048, QK + 1024, 2048, Sb, S, D, 0.03125f, 0, 4, 8, 4, lr, nullptr);

    // 4) P[z] = expS @ V, split-K=4 (M=4096, N=1024, Ksplit=1024 of K=4096)
    //    grid 4x16x4; panels per z: bnW=1, bmW=8, numPanelX=4
    gemm_bt<0><<<dim3(4, 16, 4), 512, 0, stream>>>(
        Sb, S, Vt, S, P, D, 1024, 1.0f, (size_t)S * D, 1, 8, 4, nullptr, nullptr);

    // 5) out = (P0+P1+P2+P3) / l[row]
    add_div4<<<(S * D) / (8 * 256), 256, 0, stream>>>(P, lr, out);
}